// Round 13
// baseline (456.446 us; speedup 1.0000x reference)
//
#include <hip/hip_runtime.h>
#include <hip/hip_bf16.h>

#define NROW 8192
#define DDIM 1024          // bytes per fp8 row
#define TINV 2.0f          // 1 / TEMPERATURE
#define SCALE1 0x7F7F7F7F  // e8m0 = 127 in every byte -> scale 1.0

typedef __attribute__((ext_vector_type(4))) float f32x4;
typedef __attribute__((ext_vector_type(4))) int   i32x4;
typedef __attribute__((ext_vector_type(8))) int   i32x8;

// ---- manual f32 -> fp8 e4m3fn (OCP), RNE, saturating ----
__device__ __forceinline__ unsigned f2fp8(float x) {
  unsigned b = __float_as_uint(x);
  unsigned sgn = (b >> 24) & 0x80u;
  float af = __uint_as_float(b & 0x7FFFFFFFu);
  if (af >= 448.0f) return sgn | 0x7Eu;
  if (af < 0.015625f) {
    unsigned q = (unsigned)__float2int_rn(af * 512.0f);
    return sgn | q;
  }
  unsigned ab = b & 0x7FFFFFFFu;
  unsigned m  = ab & 0x7FFFFFu;
  unsigned m3 = m >> 20;
  unsigned rem = m & 0xFFFFFu;
  unsigned rnd = (rem > 0x80000u) || (rem == 0x80000u && (m3 & 1u));
  unsigned e  = (ab >> 23) - 120u;
  return sgn | ((e << 3) + m3 + rnd);
}

// ---------------------------------------------------------------------------
// Fragment layout for z1f/z2f (written by normalize, read by GEMM):
//   addr = rowgroup(row>>4)*16384 + kchunk(byte/16)*256 + (row&15)*16 + byte%16
// A wave's MFMA fragment load is then 2 coalesced global_load_dwordx4
// (4 x 256B segments per instruction). Per-lane k-bytes = [kt*128+lgrp*32,+32)
// -- the same permutation for A and B, so it cancels in the dot product.
// ---------------------------------------------------------------------------

// Kernel 1: per-row L2 norms, diag (fp32-exact), fp8 normalized copies in
// fragment layout (z1 pre-scaled by 1/T; power-of-2 scale = exact).
__global__ __launch_bounds__(256) void normalize_diag(
    const float* __restrict__ v1, const float* __restrict__ v2,
    unsigned char* __restrict__ z1f, unsigned char* __restrict__ z2f,
    float* __restrict__ diag)
{
  const int row = blockIdx.x;
  const int t = threadIdx.x;
  const float4 a = ((const float4*)(v1 + (size_t)row * 1024))[t];
  const float4 b = ((const float4*)(v2 + (size_t)row * 1024))[t];
  float s1 = a.x*a.x + a.y*a.y + a.z*a.z + a.w*a.w;
  float s2 = b.x*b.x + b.y*b.y + b.z*b.z + b.w*b.w;
  float sd = a.x*b.x + a.y*b.y + a.z*b.z + a.w*b.w;
  #pragma unroll
  for (int m = 1; m < 64; m <<= 1) {
    s1 += __shfl_xor(s1, m);
    s2 += __shfl_xor(s2, m);
    sd += __shfl_xor(sd, m);
  }
  __shared__ float red[3][4];
  const int w = t >> 6;
  if ((t & 63) == 0) { red[0][w] = s1; red[1][w] = s2; red[2][w] = sd; }
  __syncthreads();
  s1 = red[0][0] + red[0][1] + red[0][2] + red[0][3];
  s2 = red[1][0] + red[1][1] + red[1][2] + red[1][3];
  sd = red[2][0] + red[2][1] + red[2][2] + red[2][3];
  const float i1 = 1.0f / fmaxf(sqrtf(s1), 1e-12f);
  const float i2 = 1.0f / fmaxf(sqrtf(s2), 1e-12f);
  if (t == 0) diag[row] = sd * i1 * i2 * TINV;
  const float sc1 = i1 * TINV;
  unsigned o1 = f2fp8(a.x*sc1) | (f2fp8(a.y*sc1) << 8)
              | (f2fp8(a.z*sc1) << 16) | (f2fp8(a.w*sc1) << 24);
  unsigned o2 = f2fp8(b.x*i2)  | (f2fp8(b.y*i2)  << 8)
              | (f2fp8(b.z*i2) << 16) | (f2fp8(b.w*i2)  << 24);
  // fragment-layout address of this thread's 4 bytes (byte col = t*4):
  const size_t off = (size_t)(row >> 4) * 16384 + (size_t)(t >> 2) * 256
                   + (size_t)(row & 15) * 16 + (size_t)(t & 3) * 4;
  *(unsigned*)(z1f + off) = o1;
  *(unsigned*)(z2f + off) = o2;
}

// ---------------------------------------------------------------------------
// Kernel 2: 128x128-tile MX-fp8 GEMM (sim = z1*z2^T) + fused exp-rowsum.
// ALL-REGISTER pipeline: A and B fragments load straight from global
// (fragment-layout z1f/z2f) -- zero LDS in the K-loop, zero barriers,
// compiler-tracked vmcnt via register deps. 256 thr / 4 waves (2M x 2N),
// 64x64 per wave (acc=64), ping/pong one-tile prefetch (~210 VGPR < 256
// cap at (256,2) -> 2 waves/SIMD, 2 blocks/CU).
// The previous LDS design was 6-8x LDS-pipe-bound (1536 cyc ds_read vs 244
// cyc MFMA per CU-tile); this moves operand traffic to the TA/L1/L2 path.
// ---------------------------------------------------------------------------
#define KTILES 8

__global__ __launch_bounds__(256, 2) void gemm_rowsum(
    const unsigned char* __restrict__ z1f,
    const unsigned char* __restrict__ z2f,
    float* __restrict__ partial)
{
  __shared__ float rs[2][128];      // epilogue only (1 KB)

  const int bid = blockIdx.x;
  const int bi = bid >> 6;          // 64 row-blocks
  const int bj = bid & 63;          // 64 col-blocks
  const int t = threadIdx.x;
  const int w = t >> 6;             // wave 0..3
  const int lane = t & 63;
  const int wr = w >> 1;            // 0..1: A rows wr*64
  const int wc = w & 1;             // 0..1: B cols wc*64
  const int lcol = lane & 15;
  const int lgrp = lane >> 4;       // 0..3

  // per-wave fragment base pointers (lane-resolved)
  const unsigned char* Abase = z1f + (size_t)(bi*8 + wr*4) * 16384
                             + (size_t)lgrp * 512 + (size_t)lcol * 16;
  const unsigned char* Bbase = z2f + (size_t)(bj*8 + wc*4) * 16384
                             + (size_t)lgrp * 512 + (size_t)lcol * 16;

  f32x4 acc[4][4];
  #pragma unroll
  for (int i = 0; i < 4; ++i)
    #pragma unroll
    for (int j = 0; j < 4; ++j)
      acc[i][j] = (f32x4){0.f, 0.f, 0.f, 0.f};

  // fragment load: two dwordx4, 256B apart; concat into the 8-reg operand
#define LF(DST, BASE, MT, KT) do {                                            \
    i32x4 lo_ = *(const i32x4*)((BASE) + (size_t)(MT)*16384 + (size_t)(KT)*2048); \
    i32x4 hi_ = *(const i32x4*)((BASE) + (size_t)(MT)*16384 + (size_t)(KT)*2048 + 256); \
    DST = __builtin_shufflevector(lo_, hi_, 0,1,2,3,4,5,6,7);                 \
  } while (0)

#define LOADTILE(A0,A1,A2,A3,B0,B1,B2,B3,KT)                                  \
  do { LF(A0, Abase, 0, KT); LF(A1, Abase, 1, KT);                            \
       LF(A2, Abase, 2, KT); LF(A3, Abase, 3, KT);                            \
       LF(B0, Bbase, 0, KT); LF(B1, Bbase, 1, KT);                            \
       LF(B2, Bbase, 2, KT); LF(B3, Bbase, 3, KT); } while (0)

#define MF(MT, NT, AA, BB)                                                    \
  acc[MT][NT] = __builtin_amdgcn_mfma_scale_f32_16x16x128_f8f6f4(             \
      AA, BB, acc[MT][NT], 0, 0, 0, SCALE1, 0, SCALE1)

#define MFMA16(A0,A1,A2,A3,B0,B1,B2,B3)                                       \
  do { MF(0,0,A0,B0); MF(1,1,A1,B1); MF(2,2,A2,B2); MF(3,3,A3,B3);            \
       MF(0,1,A0,B1); MF(1,0,A1,B0); MF(2,3,A2,B3); MF(3,2,A3,B2);            \
       MF(0,2,A0,B2); MF(1,3,A1,B3); MF(2,0,A2,B0); MF(3,1,A3,B1);            \
       MF(0,3,A0,B3); MF(1,2,A1,B2); MF(2,1,A2,B1); MF(3,0,A3,B0); } while (0)

  i32x8 pa0,pa1,pa2,pa3, pb0,pb1,pb2,pb3;
  i32x8 qa0,qa1,qa2,qa3, qb0,qb1,qb2,qb3;

  // prologue: tile 0 into ping
  LOADTILE(pa0,pa1,pa2,pa3, pb0,pb1,pb2,pb3, 0);

  #pragma unroll
  for (int kt = 0; kt < KTILES; kt += 2) {
    // issue tile kt+1 into pong (compiler waits ping via reg deps)
    LOADTILE(qa0,qa1,qa2,qa3, qb0,qb1,qb2,qb3, kt + 1);
    MFMA16(pa0,pa1,pa2,pa3, pb0,pb1,pb2,pb3);
    if (kt + 2 < KTILES)
      LOADTILE(pa0,pa1,pa2,pa3, pb0,pb1,pb2,pb3, kt + 2);
    MFMA16(qa0,qa1,qa2,qa3, qb0,qb1,qb2,qb3);
  }

  // ---- epilogue: exp + per-row sum over this block's 128 cols ----
  // C/D layout (shape-determined): col = lane&15, row = lgrp*4 + reg.
  #pragma unroll
  for (int mt = 0; mt < 4; ++mt) {
    #pragma unroll
    for (int r = 0; r < 4; ++r) {
      float s = __expf(acc[mt][0][r]) + __expf(acc[mt][1][r])
              + __expf(acc[mt][2][r]) + __expf(acc[mt][3][r]);
      s += __shfl_xor(s, 1);
      s += __shfl_xor(s, 2);
      s += __shfl_xor(s, 4);
      s += __shfl_xor(s, 8);
      if (lcol == 0)
        rs[wc][wr * 64 + mt * 16 + lgrp * 4 + r] = s;
    }
  }
  __syncthreads();
  if (t < 128)
    partial[(size_t)bj * NROW + bi * 128 + t] = rs[0][t] + rs[1][t];
}

// ---------------------------------------------------------------------------
// Kernel 3: per-row loss = log(sum of 64 partials) - diag; block partial sums.
// ---------------------------------------------------------------------------
__global__ __launch_bounds__(256) void rowloss(
    const float* __restrict__ partial, const float* __restrict__ diag,
    float* __restrict__ blocksum)
{
  const int i = blockIdx.x * 256 + threadIdx.x;
  float s = 0.f;
  #pragma unroll 8
  for (int b = 0; b < 64; ++b) s += partial[(size_t)b * NROW + i];
  float loss = logf(s) - diag[i];
  #pragma unroll
  for (int m = 1; m < 64; m <<= 1) loss += __shfl_xor(loss, m);
  __shared__ float red[4];
  if ((threadIdx.x & 63) == 0) red[threadIdx.x >> 6] = loss;
  __syncthreads();
  if (threadIdx.x == 0)
    blocksum[blockIdx.x] = red[0] + red[1] + red[2] + red[3];
}

__global__ void finalize(const float* __restrict__ blocksum,
                         float* __restrict__ out)
{
  float s = (threadIdx.x < 32) ? blocksum[threadIdx.x] : 0.f;
  #pragma unroll
  for (int m = 1; m < 64; m <<= 1) s += __shfl_xor(s, m);
  if (threadIdx.x == 0) out[0] = s * (1.0f / NROW);
}

// ---------------------------------------------------------------------------
extern "C" void kernel_launch(void* const* d_in, const int* in_sizes, int n_in,
                              void* d_out, int out_size, void* d_ws, size_t ws_size,
                              hipStream_t stream) {
  const float* v1 = (const float*)d_in[0];
  const float* v2 = (const float*)d_in[1];
  float* out = (float*)d_out;

  char* ws = (char*)d_ws;
  // layout: z1f (8MB) | z2f (8MB) | diag (32KB) | partial (2MB) | blocksum
  unsigned char* z1f = (unsigned char*)ws;
  unsigned char* z2f = (unsigned char*)(ws + (size_t)NROW * DDIM);
  float* diag = (float*)(ws + (size_t)NROW * DDIM * 2);
  float* partial = (float*)(ws + (size_t)NROW * DDIM * 2 + (size_t)NROW * 4);
  float* blocksum = (float*)(ws + (size_t)NROW * DDIM * 2 + (size_t)NROW * 4
                             + (size_t)64 * NROW * 4);

  normalize_diag<<<NROW, 256, 0, stream>>>(v1, v2, z1f, z2f, diag);
  gemm_rowsum<<<64 * 64, 256, 0, stream>>>(z1f, z2f, partial);
  rowloss<<<NROW / 256, 256, 0, stream>>>(partial, diag, blocksum);
  finalize<<<1, 64, 0, stream>>>(blocksum, out);
}